// Round 14
// baseline (128.005 us; speedup 1.0000x reference)
//
#include <hip/hip_runtime.h>

#define S_LEN 2048
#define E_DIM 512
#define NTOK  16384   // B*S = 8*2048
#define NOFF  4096    // offsets blocks (4 tokens each)
#define NWCVT 512     // weight-cvt blocks: ipw 384 | outw 128 (2048 elems each)

typedef __bf16 bf16x8_t __attribute__((ext_vector_type(8)));
typedef float f32x4_t __attribute__((ext_vector_type(4)));
typedef unsigned short u16x8_t __attribute__((ext_vector_type(8)));

__device__ __forceinline__ float bf2f(unsigned short h) {
  return __uint_as_float(((unsigned)h) << 16);
}
// native casts -> compiler emits v_cvt_pk_bf16_f32 (m240: don't hand-roll)
__device__ __forceinline__ u16x8_t cvt8n(float4 a, float4 b) {
  bf16x8_t t;
  t[0] = (__bf16)a.x; t[1] = (__bf16)a.y; t[2] = (__bf16)a.z; t[3] = (__bf16)a.w;
  t[4] = (__bf16)b.x; t[5] = (__bf16)b.y; t[6] = (__bf16)b.z; t[7] = (__bf16)b.w;
  union { bf16x8_t h; u16x8_t u; } cv; cv.h = t; return cv.u;
}
// async global->LDS, 16B per lane; LDS dest = wave-uniform base + lane*16
__device__ __forceinline__ void gload16(const void* g, void* l) {
  __builtin_amdgcn_global_load_lds(
      (const __attribute__((address_space(1))) unsigned int*)g,
      (__attribute__((address_space(3))) unsigned int*)l, 16, 0, 0);
}

// ---------------- offsets (blocks < NOFF) + weight fp32->bf16 cvt (appended blocks) ----------------
__global__ __launch_bounds__(256)
void offsets_kernel(const float* __restrict__ q, const float* __restrict__ ipw,
                    const float* __restrict__ outw, const float* __restrict__ ow,
                    const float* __restrict__ ob, int* __restrict__ idx,
                    unsigned short* __restrict__ Wb, unsigned short* __restrict__ OWb)
{
  const int bid = blockIdx.x;
  if (bid >= NOFF) {
    // weight cvt: 2048 elems per block (ipw 384 blocks, outw 128)
    const int cb = bid - NOFF;
    const float* src; unsigned short* dst; size_t base;
    if (cb < 384) { src = ipw;  dst = Wb;  base = (size_t)cb * 2048; }
    else          { src = outw; dst = OWb; base = (size_t)(cb - 384) * 2048; }
    const size_t e = base + (size_t)threadIdx.x * 8;
    const float4 a = *(const float4*)(src + e);
    const float4 b = *(const float4*)(src + e + 4);
    *(u16x8_t*)(dst + e) = cvt8n(a, b);
    return;
  }
  // one wave per token; w rows L1-broadcast; butterfly reduce (fp32 exact-path)
  const int wid  = threadIdx.x >> 6;
  const int lane = threadIdx.x & 63;
  const int n = bid * 4 + wid;                 // token
  const int s = n & (S_LEN - 1);
  const float* qr = q + (size_t)n * E_DIM + lane * 8;
  const float4 q0 = *(const float4*)qr;
  const float4 q1 = *(const float4*)(qr + 4);
  float myoff = 0.f;
  #pragma unroll
  for (int p = 0; p < 8; ++p) {
    const float* wr = ow + (size_t)(2 * p) * E_DIM + lane * 8;   // row 2p = offsets[...,0]
    const float4 w0 = *(const float4*)wr;
    const float4 w1 = *(const float4*)(wr + 4);
    float acc = q0.x*w0.x + q0.y*w0.y + q0.z*w0.z + q0.w*w0.w
              + q1.x*w1.x + q1.y*w1.y + q1.z*w1.z + q1.w*w1.w;
    #pragma unroll
    for (int d = 32; d; d >>= 1) acc += __shfl_xor(acc, d, 64);
    if ((lane & 7) == p) myoff = acc;
  }
  if (lane < 8) {
    float off = myoff + ob[2 * lane];
    float val = (float)s + off;
    int id = (int)truncf(val);                 // trunc toward zero, then clip (matches ref)
    id = id < 0 ? 0 : (id > S_LEN - 1 ? S_LEN - 1 : id);
    idx[n * 8 + lane] = id;
  }
}

// ---------------- bf16 MFMA GEMM: C(16384 x 512) = A @ W^T + bias ----------------
// Round-5 structure (128x128 tile, BK=64, 4 waves of 64x64, dbuf 64 KB, 2 blocks/CU).
// A_FP32=1: A read fp32 (q/k/v direct, NO cvt prepass) via reg-stage + cvt_pk +
//   swizzled ds_write (T14 split: loads before MFMA, writes after). B via gload16.
// A_FP32=0: A bf16 via gload16 (pre-swizzled source, rule #21).
// Grid (m, n, z): same-m blocks 128 apart -> same XCD -> A-panel L2-reuse.
template<int A_FP32, int OUT_BF16>
__global__ __launch_bounds__(256, 2)
void gemm_kernel(const void* __restrict__ A0v, const void* __restrict__ A1v,
                 const void* __restrict__ A2v, const unsigned short* __restrict__ W,
                 const float* __restrict__ bias, void* __restrict__ Cout)
{
  __shared__ __align__(16) unsigned short sA[2][128 * 64];
  __shared__ __align__(16) unsigned short sB[2][128 * 64];

  const int z = blockIdx.z;
  const void* Av = (z == 0) ? A0v : ((z == 1) ? A1v : A2v);
  const float* Af = (const float*)Av;
  const unsigned short* Ab = (const unsigned short*)Av;
  const unsigned short* Wz = W + (size_t)z * E_DIM * E_DIM;
  const float* bz = bias + (size_t)z * E_DIM;

  const int t    = threadIdx.x;
  const int lane = t & 63;
  const int wid  = t >> 6;        // 0..3
  const int wm   = wid >> 1;      // 0..1
  const int wn   = wid & 1;       // 0..1
  const size_t m0 = (size_t)blockIdx.x * 128;
  const size_t n0 = (size_t)blockIdx.y * 128;

  // B staging (and A when bf16): gload16, pre-swizzled source chunk = (lane&7)^(lane>>3)
  const int srow0  = wid * 32;
  const int schunk = (lane & 7) ^ (lane >> 3);
  const unsigned short* gB = Wz + (n0 + srow0 + (lane >> 3)) * E_DIM + schunk * 8;
  const unsigned short* gA = Ab + (m0 + srow0 + (lane >> 3)) * E_DIM + schunk * 8;

  // A fp32 staging: thread t -> row t>>1, chunks (t&1)*4+{0..3} (8 bf16 each)
  const int arow  = t >> 1;
  const int cbase = (t & 1) * 4;
  const float* gAf = Af + (m0 + arow) * E_DIM + cbase * 8;
  float4 a_r[8];

#define B_STAGE(buf, k0) do { \
    _Pragma("unroll") \
    for (int i_ = 0; i_ < 4; ++i_) \
      gload16(gB + (size_t)(i_ * 8) * E_DIM + (k0), &sB[buf][(srow0 + i_ * 8) * 64]); \
  } while (0)
#define AB_STAGE(buf, k0) do { \
    _Pragma("unroll") \
    for (int i_ = 0; i_ < 4; ++i_) \
      gload16(gA + (size_t)(i_ * 8) * E_DIM + (k0), &sA[buf][(srow0 + i_ * 8) * 64]); \
  } while (0)
#define A_LOAD(k0) do { \
    _Pragma("unroll") \
    for (int c_ = 0; c_ < 4; ++c_) { \
      const float* ap = gAf + (k0) + c_ * 8; \
      a_r[2 * c_]     = *(const float4*)ap; \
      a_r[2 * c_ + 1] = *(const float4*)(ap + 4); \
    } } while (0)
#define A_WRITE(buf) do { \
    _Pragma("unroll") \
    for (int c_ = 0; c_ < 4; ++c_) { \
      const int c = cbase + c_; \
      *(u16x8_t*)&sA[buf][arow * 64 + ((c ^ (arow & 7)) << 3)] = cvt8n(a_r[2 * c_], a_r[2 * c_ + 1]); \
    } } while (0)

  f32x4_t acc[4][4];
  #pragma unroll
  for (int i = 0; i < 4; ++i)
    #pragma unroll
    for (int j = 0; j < 4; ++j)
      acc[i][j] = (f32x4_t){0.f, 0.f, 0.f, 0.f};

  // prologue: stage tile 0
  if constexpr (A_FP32) { A_LOAD(0); B_STAGE(0, 0); A_WRITE(0); }
  else                  { AB_STAGE(0, 0); B_STAGE(0, 0); }
  int cur = 0;
  const int fr = lane & 15;
  const int ck0 = lane >> 4;      // fragment k-chunk base (0..3)

  for (int kt = 0; kt < 8; ++kt) {            // 512 / 64
    __syncthreads();                          // vmcnt+lgkm drained: tile cur complete
    if (kt < 7) {
      if constexpr (A_FP32) { A_LOAD((kt + 1) * 64); B_STAGE(cur ^ 1, (kt + 1) * 64); }
      else                  { AB_STAGE(cur ^ 1, (kt + 1) * 64); B_STAGE(cur ^ 1, (kt + 1) * 64); }
    }
    #pragma unroll
    for (int kk = 0; kk < 64; kk += 32) {
      const int ckb = (kk >> 3) + ck0;        // 0..7
      bf16x8_t af[4], bfv[4];
      #pragma unroll
      for (int i = 0; i < 4; ++i) {
        const int ra = wm * 64 + i * 16 + fr;
        af[i] = *(const bf16x8_t*)&sA[cur][ra * 64 + ((ckb ^ (ra & 7)) << 3)];
      }
      #pragma unroll
      for (int j = 0; j < 4; ++j) {
        const int rb = wn * 64 + j * 16 + fr;
        bfv[j] = *(const bf16x8_t*)&sB[cur][rb * 64 + ((ckb ^ (rb & 7)) << 3)];
      }
      #pragma unroll
      for (int i = 0; i < 4; ++i)
        #pragma unroll
        for (int j = 0; j < 4; ++j)
          acc[i][j] = __builtin_amdgcn_mfma_f32_16x16x32_bf16(af[i], bfv[j], acc[i][j], 0, 0, 0);
    }
    if (kt < 7) {
      if constexpr (A_FP32) A_WRITE(cur ^ 1);   // loads landed under MFMA; write-late (T14)
    }
    cur ^= 1;
  }
#undef B_STAGE
#undef AB_STAGE
#undef A_LOAD
#undef A_WRITE

  // Epilogue: D row = (lane>>4)*4 + r, col = lane&15  (m89-verified C/D layout)
  unsigned short* Cb = (unsigned short*)Cout + (size_t)z * NTOK * E_DIM;
  float* Cf = (float*)Cout;
  #pragma unroll
  for (int i = 0; i < 4; ++i) {
    const int row = (int)m0 + wm * 64 + i * 16 + (lane >> 4) * 4;
    #pragma unroll
    for (int j = 0; j < 4; ++j) {
      const int col = (int)n0 + wn * 64 + j * 16 + fr;
      const float bv = bz[col];
      #pragma unroll
      for (int r = 0; r < 4; ++r) {
        const float val = acc[i][j][r] + bv;
        if constexpr (OUT_BF16)
          Cb[(size_t)(row + r) * E_DIM + col] = __builtin_bit_cast(unsigned short, (__bf16)val);
        else
          Cf[(size_t)(row + r) * E_DIM + col] = val;
      }
    }
  }
}

// ---------------- attention: gather projected rows, softmax over P=8, ctx (bf16) ----------------
__global__ __launch_bounds__(256)
void attn_kernel(const unsigned short* __restrict__ Qp, const unsigned short* __restrict__ Kp,
                 const unsigned short* __restrict__ Vp, const int* __restrict__ idx,
                 unsigned short* __restrict__ ctx)
{
  const int wid  = threadIdx.x >> 6;
  const int lane = threadIdx.x & 63;
  const int n = blockIdx.x * 4 + wid;
  const int b = n >> 11;
  const int h = lane >> 3;
  const int p = lane & 7;

  const int id = idx[n * 8 + p];
  const size_t krow = ((size_t)(b << 11) + id) * E_DIM + h * 64;
  const unsigned short* qb = Qp + (size_t)n * E_DIM + h * 64;

  float sc = 0.f;
  #pragma unroll
  for (int j = 0; j < 8; ++j) {
    u16x8_t qv = *(const u16x8_t*)(qb + j * 8);
    u16x8_t kv = *(const u16x8_t*)(Kp + krow + j * 8);
    #pragma unroll
    for (int e = 0; e < 8; ++e) sc += bf2f(qv[e]) * bf2f(kv[e]);
  }
  sc *= 0.125f;  // 1/sqrt(64)

  float m = sc;
  m = fmaxf(m, __shfl_xor(m, 1, 64));
  m = fmaxf(m, __shfl_xor(m, 2, 64));
  m = fmaxf(m, __shfl_xor(m, 4, 64));
  const float ex = __expf(sc - m);
  float dsum = ex;
  dsum += __shfl_xor(dsum, 1, 64);
  dsum += __shfl_xor(dsum, 2, 64);
  dsum += __shfl_xor(dsum, 4, 64);
  const float attn = ex / dsum;

  const int d0 = p * 8;
  float cacc[8];
  #pragma unroll
  for (int j = 0; j < 8; ++j) cacc[j] = 0.f;
  #pragma unroll
  for (int pp = 0; pp < 8; ++pp) {
    const float ap = __shfl(attn, (lane & 56) + pp, 64);
    const int  idp = __shfl(id,   (lane & 56) + pp, 64);
    const unsigned short* vb = Vp + ((size_t)(b << 11) + idp) * E_DIM + h * 64 + d0;
    u16x8_t vv = *(const u16x8_t*)vb;
    #pragma unroll
    for (int j = 0; j < 8; ++j) cacc[j] += ap * bf2f(vv[j]);
  }
  u16x8_t cc;
  #pragma unroll
  for (int j = 0; j < 8; ++j) cc[j] = __builtin_bit_cast(unsigned short, (__bf16)cacc[j]);
  *(u16x8_t*)(ctx + (size_t)n * E_DIM + h * 64 + d0) = cc;
}

extern "C" void kernel_launch(void* const* d_in, const int* in_sizes, int n_in,
                              void* d_out, int out_size, void* d_ws, size_t ws_size,
                              hipStream_t stream) {
  const float* q        = (const float*)d_in[0];
  const float* k        = (const float*)d_in[1];
  const float* v        = (const float*)d_in[2];
  const float* offset_w = (const float*)d_in[3];
  const float* offset_b = (const float*)d_in[4];
  const float* in_proj_w = (const float*)d_in[5];
  const float* in_proj_b = (const float*)d_in[6];
  const float* out_w    = (const float*)d_in[7];
  const float* out_b    = (const float*)d_in[8];

  char* ws = (char*)d_ws;
  // ws layout (u16 elements): Wb(786432) | OWb(262144) | Qp | Kp | Vp | ctx | idx(int)
  unsigned short* Wb   = (unsigned short*)ws;
  unsigned short* OWb  = Wb + (size_t)3 * E_DIM * E_DIM;
  unsigned short* Qp   = OWb + (size_t)E_DIM * E_DIM;
  unsigned short* Kp   = Qp + (size_t)NTOK * E_DIM;
  unsigned short* Vp   = Kp + (size_t)NTOK * E_DIM;
  unsigned short* ctxb = Vp + (size_t)NTOK * E_DIM;
  int* idxb = (int*)(ctxb + (size_t)NTOK * E_DIM);

  offsets_kernel<<<NOFF + NWCVT, 256, 0, stream>>>(q, in_proj_w, out_w, offset_w, offset_b,
                                                   idxb, Wb, OWb);
  gemm_kernel<1, 1><<<dim3(NTOK / 128, E_DIM / 128, 3), 256, 0, stream>>>(
      q, k, v, Wb, in_proj_b, (void*)Qp);
  attn_kernel<<<NTOK / 4, 256, 0, stream>>>(Qp, Kp, Vp, idxb, ctxb);
  gemm_kernel<0, 0><<<dim3(NTOK / 128, E_DIM / 128, 1), 256, 0, stream>>>(
      ctxb, ctxb, ctxb, OWb, out_b, d_out);
}

// Round 15
// 102.409 us; speedup vs baseline: 1.2499x; 1.2499x over previous
//
#include <hip/hip_runtime.h>

#define S_LEN 2048
#define E_DIM 512
#define NTOK  16384   // B*S = 8*2048
#define QBLK  1024    // prepass q-part blocks: 4 waves x 4 tokens = 16 tokens/block
#define CVTBLK 4096   // prepass cvt blocks (grid-stride)

typedef __bf16 bf16x8_t __attribute__((ext_vector_type(8)));
typedef __bf16 bf16x4_t __attribute__((ext_vector_type(4)));
typedef float f32x4_t __attribute__((ext_vector_type(4)));
typedef unsigned short u16x8_t __attribute__((ext_vector_type(8)));
typedef unsigned short u16x4_t __attribute__((ext_vector_type(4)));

__device__ __forceinline__ float bf2f(unsigned short h) {
  return __uint_as_float(((unsigned)h) << 16);
}
// native casts -> compiler emits v_cvt_pk_bf16_f32 (m240: don't hand-roll)
__device__ __forceinline__ u16x8_t cvt8n(float4 a, float4 b) {
  bf16x8_t t;
  t[0] = (__bf16)a.x; t[1] = (__bf16)a.y; t[2] = (__bf16)a.z; t[3] = (__bf16)a.w;
  t[4] = (__bf16)b.x; t[5] = (__bf16)b.y; t[6] = (__bf16)b.z; t[7] = (__bf16)b.w;
  union { bf16x8_t h; u16x8_t u; } cv; cv.h = t; return cv.u;
}
__device__ __forceinline__ u16x4_t cvt4n(float4 a) {
  bf16x4_t t;
  t[0] = (__bf16)a.x; t[1] = (__bf16)a.y; t[2] = (__bf16)a.z; t[3] = (__bf16)a.w;
  union { bf16x4_t h; u16x4_t u; } cv; cv.h = t; return cv.u;
}
// async global->LDS, 16B per lane; LDS dest = wave-uniform base + lane*16
__device__ __forceinline__ void gload16(const void* g, void* l) {
  __builtin_amdgcn_global_load_lds(
      (const __attribute__((address_space(1))) unsigned int*)g,
      (__attribute__((address_space(3))) unsigned int*)l, 16, 0, 0);
}

// ---------------- prepass ----------------
// blocks [0, QBLK): offsets (lane-parallel LDS dot) + q->bf16.
// blocks [QBLK, QBLK+CVTBLK): grid-stride fp32->bf16 cvt of k|v|ipw|outw (16B granules).
__global__ __launch_bounds__(256)
void prepass_kernel(const float* __restrict__ q, const float* __restrict__ k,
                    const float* __restrict__ v, const float* __restrict__ ipw,
                    const float* __restrict__ outw, const float* __restrict__ ow,
                    const float* __restrict__ ob, int* __restrict__ idx,
                    unsigned short* __restrict__ Qbf, unsigned short* __restrict__ Kb,
                    unsigned short* __restrict__ Vb, unsigned short* __restrict__ Wb,
                    unsigned short* __restrict__ OWb)
{
  const int bid = blockIdx.x;
  if (bid >= QBLK) {
    // granule = 4 fp32 = 16B read / 8B write. Segment bounds in granules:
    // k: 2097152 | v: +2097152 | ipw: 196608 | outw: 65536
    const size_t NG = 4456448;
    const size_t gstride = (size_t)CVTBLK * 256;
    for (size_t g = (size_t)(bid - QBLK) * 256 + threadIdx.x; g < NG; g += gstride) {
      const float* src; unsigned short* dst; size_t e;
      if (g < 2097152)      { src = k;    dst = Kb;  e = g * 4; }
      else if (g < 4194304) { src = v;    dst = Vb;  e = (g - 2097152) * 4; }
      else if (g < 4390912) { src = ipw;  dst = Wb;  e = (g - 4194304) * 4; }
      else                  { src = outw; dst = OWb; e = (g - 4390912) * 4; }
      *(u16x4_t*)(dst + e) = cvt4n(*(const float4*)(src + e));
    }
    return;
  }

  // ---- offsets + q->bf16, 16 tokens per block (lane-parallel partial dots) ----
  __shared__ float wl[8][548];   // even offset_w rows 0,2,..,14 (elem e -> (e>>6)*68 + (e&63))
  __shared__ float ql[4][548];   // one token row per wave

  {
    const int r  = threadIdx.x >> 5;            // 0..7
    const int e0 = (threadIdx.x & 31) * 16;
    const float* src = ow + (size_t)(2 * r) * E_DIM + e0;
    #pragma unroll
    for (int c = 0; c < 4; ++c) {
      const int e = e0 + c * 4;
      *(float4*)&wl[r][(e >> 6) * 68 + (e & 63)] = *(const float4*)(src + c * 4);
    }
  }
  __syncthreads();

  const int w    = threadIdx.x >> 6;
  const int lane = threadIdx.x & 63;
  const int j    = lane >> 3;     // segment 0..7 (64 elems each)
  const int p    = lane & 7;      // sample 0..7

  for (int it = 0; it < 4; ++it) {
    const int n = bid * 16 + w * 4 + it;
    const float* qr = q + (size_t)n * E_DIM + lane * 8;
    const float4 q0 = *(const float4*)qr;
    const float4 q1 = *(const float4*)(qr + 4);
    *(u16x8_t*)(Qbf + (size_t)n * E_DIM + lane * 8) = cvt8n(q0, q1);
    const int e  = lane * 8;
    const int ph = (e >> 6) * 68 + (e & 63);
    *(float4*)&ql[w][ph]     = q0;
    *(float4*)&ql[w][ph + 4] = q1;

    float acc = 0.f;
    #pragma unroll
    for (int i4 = 0; i4 < 16; ++i4) {
      const float4 qv = *(const float4*)&ql[w][j * 68 + i4 * 4];
      const float4 wv = *(const float4*)&wl[p][j * 68 + i4 * 4];
      acc = fmaf(qv.x, wv.x, acc); acc = fmaf(qv.y, wv.y, acc);
      acc = fmaf(qv.z, wv.z, acc); acc = fmaf(qv.w, wv.w, acc);
    }
    acc += __shfl_xor(acc, 8, 64);
    acc += __shfl_xor(acc, 16, 64);
    acc += __shfl_xor(acc, 32, 64);
    if (lane < 8) {
      const float val = (float)(n & (S_LEN - 1)) + acc + ob[2 * lane];
      int id = (int)truncf(val);               // trunc toward zero, then clip (matches ref)
      id = id < 0 ? 0 : (id > S_LEN - 1 ? S_LEN - 1 : id);
      idx[n * 8 + lane] = id;
    }
    __syncthreads();   // ql[w] reuse guard
  }
}

// ---------------- z-fused qkv GEMM: for z in {q,k,v}: C_z = A_z @ W_z^T + b_z ----------------
// Round-5 inner structure (128x128 tile, BK=64, 4 waves of 64x64, dbuf 64 KB, gload16,
// pre-swizzled source chunk^(row&7), 2 blocks/CU). z fused into the block: grid (128,4)
// = 512 blocks = EXACTLY 2/CU (fixes the 384-block 25% imbalance), 24 K-steps/block.
__global__ __launch_bounds__(256, 2)
void gemm3_kernel(const unsigned short* __restrict__ Qbf, const unsigned short* __restrict__ Kbf,
                  const unsigned short* __restrict__ Vbf, const unsigned short* __restrict__ W,
                  const float* __restrict__ bias, unsigned short* __restrict__ Cout)
{
  __shared__ __align__(16) unsigned short sA[2][128 * 64];
  __shared__ __align__(16) unsigned short sB[2][128 * 64];

  const int t    = threadIdx.x;
  const int lane = t & 63;
  const int wid  = t >> 6;        // 0..3
  const int wm   = wid >> 1;      // 0..1
  const int wn   = wid & 1;       // 0..1
  const size_t m0 = (size_t)blockIdx.x * 128;
  const size_t n0 = (size_t)blockIdx.y * 128;

  const int srow0  = wid * 32;
  const int schunk = (lane & 7) ^ (lane >> 3);
  const size_t aoff = (m0 + srow0 + (lane >> 3)) * E_DIM + schunk * 8;
  const unsigned short* gA[3] = { Qbf + aoff, Kbf + aoff, Vbf + aoff };
  const unsigned short* gB = W + (n0 + srow0 + (lane >> 3)) * E_DIM + schunk * 8;

#define STAGE(buf, z_, k0) do { \
    _Pragma("unroll") \
    for (int i_ = 0; i_ < 4; ++i_) { \
      gload16(gA[z_] + (size_t)(i_ * 8) * E_DIM + (k0), &sA[buf][(srow0 + i_ * 8) * 64]); \
      gload16(gB + (size_t)(z_) * E_DIM * E_DIM + (size_t)(i_ * 8) * E_DIM + (k0), \
              &sB[buf][(srow0 + i_ * 8) * 64]); \
    } } while (0)

  f32x4_t acc[4][4];
  #pragma unroll
  for (int i = 0; i < 4; ++i)
    #pragma unroll
    for (int j = 0; j < 4; ++j)
      acc[i][j] = (f32x4_t){0.f, 0.f, 0.f, 0.f};

  STAGE(0, 0, 0);
  int cur = 0;
  const int fr = lane & 15;
  const int ck0 = lane >> 4;      // fragment k-chunk base (0..3)

  for (int it = 0; it < 24; ++it) {           // 3 z x 8 K-tiles
    const int z  = it >> 3;
    const int kt = it & 7;
    __syncthreads();                          // staged tile (cur) complete & visible
    if (it < 23) {
      const int nz = (it + 1) >> 3;
      const int nk = (it + 1) & 7;
      STAGE(cur ^ 1, nz, nk * 64);
    }
    #pragma unroll
    for (int kk = 0; kk < 64; kk += 32) {
      const int ckb = (kk >> 3) + ck0;        // 0..7
      bf16x8_t af[4], bfv[4];
      #pragma unroll
      for (int i = 0; i < 4; ++i) {
        const int ra = wm * 64 + i * 16 + fr;
        af[i] = *(const bf16x8_t*)&sA[cur][ra * 64 + ((ckb ^ (ra & 7)) << 3)];
      }
      #pragma unroll
      for (int j = 0; j < 4; ++j) {
        const int rb = wn * 64 + j * 16 + fr;
        bfv[j] = *(const bf16x8_t*)&sB[cur][rb * 64 + ((ckb ^ (rb & 7)) << 3)];
      }
      #pragma unroll
      for (int i = 0; i < 4; ++i)
        #pragma unroll
        for (int j = 0; j < 4; ++j)
          acc[i][j] = __builtin_amdgcn_mfma_f32_16x16x32_bf16(af[i], bfv[j], acc[i][j], 0, 0, 0);
    }
    if (kt == 7) {
      // Epilogue for z: D row = (lane>>4)*4 + r, col = lane&15 (m89-verified layout)
      unsigned short* Cb = Cout + (size_t)z * NTOK * E_DIM;
      #pragma unroll
      for (int i = 0; i < 4; ++i) {
        const int row = (int)m0 + wm * 64 + i * 16 + (lane >> 4) * 4;
        #pragma unroll
        for (int j = 0; j < 4; ++j) {
          const int col = (int)n0 + wn * 64 + j * 16 + fr;
          const float bv = bias[z * E_DIM + col];
          #pragma unroll
          for (int r = 0; r < 4; ++r) {
            Cb[(size_t)(row + r) * E_DIM + col] =
                __builtin_bit_cast(unsigned short, (__bf16)(acc[i][j][r] + bv));
            acc[i][j][r] = 0.f;
          }
        }
      }
    }
    cur ^= 1;
  }
#undef STAGE
}

// ---------------- out GEMM: C(16384 x 512) = ctx @ OW^T + b (bf16 in, fp32 out) ----------------
__global__ __launch_bounds__(256, 2)
void gemm_kernel(const unsigned short* __restrict__ A, const unsigned short* __restrict__ W,
                 const float* __restrict__ bias, float* __restrict__ Cf)
{
  __shared__ __align__(16) unsigned short sA[2][128 * 64];
  __shared__ __align__(16) unsigned short sB[2][128 * 64];

  const int t    = threadIdx.x;
  const int lane = t & 63;
  const int wid  = t >> 6;
  const int wm   = wid >> 1;
  const int wn   = wid & 1;
  const size_t m0 = (size_t)blockIdx.x * 128;
  const size_t n0 = (size_t)blockIdx.y * 128;

  const int srow0  = wid * 32;
  const int schunk = (lane & 7) ^ (lane >> 3);
  const unsigned short* gA = A + (m0 + srow0 + (lane >> 3)) * E_DIM + schunk * 8;
  const unsigned short* gB = W + (n0 + srow0 + (lane >> 3)) * E_DIM + schunk * 8;

#define STAGE(buf, k0) do { \
    _Pragma("unroll") \
    for (int i_ = 0; i_ < 4; ++i_) { \
      gload16(gA + (size_t)(i_ * 8) * E_DIM + (k0), &sA[buf][(srow0 + i_ * 8) * 64]); \
      gload16(gB + (size_t)(i_ * 8) * E_DIM + (k0), &sB[buf][(srow0 + i_ * 8) * 64]); \
    } } while (0)

  f32x4_t acc[4][4];
  #pragma unroll
  for (int i = 0; i < 4; ++i)
    #pragma unroll
    for (int j = 0; j < 4; ++j)
      acc[i][j] = (f32x4_t){0.f, 0.f, 0.f, 0.f};

  STAGE(0, 0);
  int cur = 0;
  const int fr = lane & 15;
  const int ck0 = lane >> 4;

  for (int kt = 0; kt < 8; ++kt) {
    __syncthreads();
    if (kt < 7) STAGE(cur ^ 1, (kt + 1) * 64);
    #pragma unroll
    for (int kk = 0; kk < 64; kk += 32) {
      const int ckb = (kk >> 3) + ck0;
      bf16x8_t af[4], bfv[4];
      #pragma unroll
      for (int i = 0; i < 4; ++i) {
        const int ra = wm * 64 + i * 16 + fr;
        af[i] = *(const bf16x8_t*)&sA[cur][ra * 64 + ((ckb ^ (ra & 7)) << 3)];
      }
      #pragma unroll
      for (int j = 0; j < 4; ++j) {
        const int rb = wn * 64 + j * 16 + fr;
        bfv[j] = *(const bf16x8_t*)&sB[cur][rb * 64 + ((ckb ^ (rb & 7)) << 3)];
      }
      #pragma unroll
      for (int i = 0; i < 4; ++i)
        #pragma unroll
        for (int j = 0; j < 4; ++j)
          acc[i][j] = __builtin_amdgcn_mfma_f32_16x16x32_bf16(af[i], bfv[j], acc[i][j], 0, 0, 0);
    }
    cur ^= 1;
  }
#undef STAGE

  #pragma unroll
  for (int i = 0; i < 4; ++i) {
    const int row = (int)m0 + wm * 64 + i * 16 + (lane >> 4) * 4;
    #pragma unroll
    for (int j = 0; j < 4; ++j) {
      const int col = (int)n0 + wn * 64 + j * 16 + fr;
      const float bv = bias[col];
      #pragma unroll
      for (int r = 0; r < 4; ++r)
        Cf[(size_t)(row + r) * E_DIM + col] = acc[i][j][r] + bv;
    }
  }
}

// ---------------- attention: gather projected rows, softmax over P=8, ctx (bf16) ----------------
__global__ __launch_bounds__(256)
void attn_kernel(const unsigned short* __restrict__ Qp, const unsigned short* __restrict__ Kp,
                 const unsigned short* __restrict__ Vp, const int* __restrict__ idx,
                 unsigned short* __restrict__ ctx)
{
  const int wid  = threadIdx.x >> 6;
  const int lane = threadIdx.x & 63;
  const int n = blockIdx.x * 4 + wid;
  const int b = n >> 11;
  const int h = lane >> 3;
  const int p = lane & 7;

  const int id = idx[n * 8 + p];
  const size_t krow = ((size_t)(b << 11) + id) * E_DIM + h * 64;
  const unsigned short* qb = Qp + (size_t)n * E_DIM + h * 64;

  float sc = 0.f;
  #pragma unroll
  for (int j = 0; j < 8; ++j) {
    u16x8_t qv = *(const u16x8_t*)(qb + j * 8);
    u16x8_t kv = *(const u16x8_t*)(Kp + krow + j * 8);
    #pragma unroll
    for (int e = 0; e < 8; ++e) sc += bf2f(qv[e]) * bf2f(kv[e]);
  }
  sc *= 0.125f;  // 1/sqrt(64)

  float m = sc;
  m = fmaxf(m, __shfl_xor(m, 1, 64));
  m = fmaxf(m, __shfl_xor(m, 2, 64));
  m = fmaxf(m, __shfl_xor(m, 4, 64));
  const float ex = __expf(sc - m);
  float dsum = ex;
  dsum += __shfl_xor(dsum, 1, 64);
  dsum += __shfl_xor(dsum, 2, 64);
  dsum += __shfl_xor(dsum, 4, 64);
  const float attn = ex / dsum;

  const int d0 = p * 8;
  float cacc[8];
  #pragma unroll
  for (int j = 0; j < 8; ++j) cacc[j] = 0.f;
  #pragma unroll
  for (int pp = 0; pp < 8; ++pp) {
    const float ap = __shfl(attn, (lane & 56) + pp, 64);
    const int  idp = __shfl(id,   (lane & 56) + pp, 64);
    const unsigned short* vb = Vp + ((size_t)(b << 11) + idp) * E_DIM + h * 64 + d0;
    u16x8_t vv = *(const u16x8_t*)vb;
    #pragma unroll
    for (int j = 0; j < 8; ++j) cacc[j] += ap * bf2f(vv[j]);
  }
  u16x8_t cc;
  #pragma unroll
  for (int j = 0; j < 8; ++j) cc[j] = __builtin_bit_cast(unsigned short, (__bf16)cacc[j]);
  *(u16x8_t*)(ctx + (size_t)n * E_DIM + h * 64 + d0) = cc;
}

extern "C" void kernel_launch(void* const* d_in, const int* in_sizes, int n_in,
                              void* d_out, int out_size, void* d_ws, size_t ws_size,
                              hipStream_t stream) {
  const float* q        = (const float*)d_in[0];
  const float* k        = (const float*)d_in[1];
  const float* v        = (const float*)d_in[2];
  const float* offset_w = (const float*)d_in[3];
  const float* offset_b = (const float*)d_in[4];
  const float* in_proj_w = (const float*)d_in[5];
  const float* in_proj_b = (const float*)d_in[6];
  const float* out_w    = (const float*)d_in[7];
  const float* out_b    = (const float*)d_in[8];

  char* ws = (char*)d_ws;
  // ws layout (u16 elements):
  // Qbf | Kbf | Vbf | Wb(786432) | OWb(262144) | Qp | Kp | Vp | idx(int)
  unsigned short* Qbf = (unsigned short*)ws;
  unsigned short* Kbf = Qbf + (size_t)NTOK * E_DIM;
  unsigned short* Vbf = Kbf + (size_t)NTOK * E_DIM;
  unsigned short* Wb  = Vbf + (size_t)NTOK * E_DIM;
  unsigned short* OWb = Wb + (size_t)3 * E_DIM * E_DIM;
  unsigned short* Qp  = OWb + (size_t)E_DIM * E_DIM;
  unsigned short* Kp  = Qp + (size_t)NTOK * E_DIM;
  unsigned short* Vp  = Kp + (size_t)NTOK * E_DIM;
  int* idxb = (int*)(Vp + (size_t)NTOK * E_DIM);
  unsigned short* ctxb = Qbf;   // alias: Qbf dead after qkv GEMM

  prepass_kernel<<<QBLK + CVTBLK, 256, 0, stream>>>(q, k, v, in_proj_w, out_w, offset_w,
                                                    offset_b, idxb, Qbf, Kbf, Vbf, Wb, OWb);
  gemm3_kernel<<<dim3(NTOK / 128, E_DIM / 128), 256, 0, stream>>>(
      Qbf, Kbf, Vbf, Wb, in_proj_b, Qp);
  attn_kernel<<<NTOK / 4, 256, 0, stream>>>(Qp, Kp, Vp, idxb, ctxb);
  gemm_kernel<<<dim3(NTOK / 128, E_DIM / 128), 256, 0, stream>>>(
      ctxb, OWb, out_b, (float*)d_out);
}